// Round 15
// baseline (152.081 us; speedup 1.0000x reference)
//
#include <hip/hip_runtime.h>
#include <hip/hip_bf16.h>

// Problem constants (QuadraticAttention): B=2, T=2048, D_MODEL=1024, H=16, d=64
#define TSEQ   2048
#define DM     1024
#define NHEAD  16
#define DH     64
#define BATCH  2
#define MR     (BATCH * TSEQ)   // 4096 rows
#define CH     64               // attention chunk length
#define NC     (TSEQ / CH)      // 32 chunks per sequence
#define QKVLD  (3 * DM)         // 3072: q|k|v packed per token row
#define LP     72               // padded LDS row stride (bf16), 144 B, 16B-aligned

typedef __attribute__((ext_vector_type(8))) short bf16x8;
typedef __attribute__((ext_vector_type(4))) float f32x4;

__device__ __forceinline__ short f2bf(float x) {
  __hip_bfloat16 h = __float2bfloat16(x);
  return *reinterpret_cast<short*>(&h);
}

// ---------------------------------------------------------------------------
// async global->LDS, 16 bytes per lane (wave-uniform base + lane*16).
// ---------------------------------------------------------------------------
__device__ __forceinline__ void stage16(const void* g, void* l) {
  __builtin_amdgcn_global_load_lds(
      (const __attribute__((address_space(1))) void*)g,
      (__attribute__((address_space(3))) void*)l, 16, 0, 0);
}

__device__ __forceinline__ void store_elem(float v, float* p) { *p = v; }
__device__ __forceinline__ void store_elem(float v, __hip_bfloat16* p) { *p = __float2bfloat16(v); }

// ---------------------------------------------------------------------------
// bf16 MFMA GEMM (measured-best body; 153.5/153.1/152.7/152.4/154.8/152.0us
// over 6 runs of identical code -> mean 153.1, noise +-1.5us):
// C[M,N] = A[M,K] @ B[K,N].  A: bf16 [M,K]. Bt: bf16 [N,K]. OutT = f32/bf16.
// Tile 128 x TN, BK=64 (16 K-iters at K=1024), 256 threads = 4 waves (2x2).
// SESSION LEDGER (do not re-derive):
//  - R6: BK=32 3-buffer counted-vmcnt pipeline = +3.4us REGRESSION (2x barrier
//    count, 4-way LDS conflicts from (row&3) XOR, sched_barrier pinning).
//  - R7: scan-fused-into-intra = +5.8us REGRESSION (runtime-bound serial
//    prefix loop exposes per-iter L2 latency; unrollable standalone scan wins).
//  - R8-R14: this body confirmed best 6x. Catalog cross-check: all
//    128^2-family alternatives (2ph, dbuf m99/m100, BK=128 m132) measure
//    at-or-below. Only proven step past it is the 8-phase 256^2 template;
//    staging choreography not derivable race-free from prose (m152).
//  - C-store packing impossible (lane holds 4 ROWS of one col, stride ldc);
//    chunk_kv+scan fusion needs grid sync (R7 failure mode); 256-wide tiles
//    kill the m114 wave-overlap. Dependency chain is fully serial.
//  - Any |delta| < ~2us is unadjudicable (noise band spans 2.8us).
// LDS rows are 128 B; T2 XOR swizzle (byte ^= (row&7)<<4) applied BOTH sides
// per rule #21: linear LDS dest for global_load_lds + inverse-XOR'd SOURCE
// column at staging + XOR'd byte address at ds_read (involution).
// XCD-aware bijective blockIdx swizzle (m204) for per-XCD L2 locality.
// ---------------------------------------------------------------------------
template <typename OutT, int TN>
__global__ __launch_bounds__(256) void gemm_bf16(const short* __restrict__ A,
                                                 const short* __restrict__ Bt,
                                                 OutT* __restrict__ C,
                                                 int M, int N, int K, int ldc) {
  constexpr int NF = TN / 32;        // B frags per wave (4 or 2)
  constexpr int BSW = TN / 32;       // B staging sweeps (TN*64*2B / 4096B)
  __shared__ short As[128][64];      // 16 KB, XOR-swizzled within 128B rows
  __shared__ short Bs[TN][64];       // 16 or 8 KB, same swizzle
  const int tid = threadIdx.x;
  const int lane = tid & 63, wid = tid >> 6;
  const int wave_m = wid >> 1, wave_n = wid & 1;

  // XCD-aware bijective swizzle: contiguous tile chunk per XCD (8 XCDs).
  const unsigned nwg = gridDim.x * gridDim.y;
  const unsigned lin = blockIdx.y * gridDim.x + blockIdx.x;
  const unsigned q8 = nwg >> 3, r8 = nwg & 7;
  const unsigned xcd = lin & 7, idx = lin >> 3;
  const unsigned swz = (xcd < r8 ? xcd * (q8 + 1) : r8 * (q8 + 1) + (xcd - r8) * q8) + idx;
  const int bx = swz % gridDim.x, by = swz / gridDim.x;

  const int row0 = by * 128, col0 = bx * TN;

  // Staging: thread t writes LDS 16B chunk (t&7) of row (t>>3), +32 rows per
  // sweep. Source column is XOR-swizzled: chunk_src = (t&7) ^ (row&7); since
  // sweep stride 32 kills &7, it is constant per thread.
  const int sr = tid >> 3;                          // 0..31
  const int scs = ((tid & 7) ^ (sr & 7)) * 8;       // source col (shorts)
  const short* Ag0 = A + (size_t)(row0 + sr) * K + scs;
  const short* Bg0 = Bt + (size_t)(col0 + sr) * K + scs;
  short* AsL = &As[0][0] + tid * 8;
  short* BsL = &Bs[0][0] + tid * 8;

  f32x4 acc[4][NF];
#pragma unroll
  for (int i = 0; i < 4; ++i)
#pragma unroll
    for (int j = 0; j < NF; ++j) acc[i][j] = (f32x4){0.f, 0.f, 0.f, 0.f};

  const int frow_a = wave_m * 64 + (lane & 15);
  const int frow_b = wave_n * (TN / 2) + (lane & 15);
  const int fk = (lane >> 4) * 8;                   // shorts within K-substep
  const int rx = (lane & 7) << 4;                   // read-side XOR (row&7)<<4

  for (int k0 = 0; k0 < K; k0 += 64) {
#pragma unroll
    for (int j = 0; j < 4; ++j)
      stage16(Ag0 + (size_t)(j * 32) * K + k0, AsL + j * 2048);
#pragma unroll
    for (int j = 0; j < BSW; ++j)
      stage16(Bg0 + (size_t)(j * 32) * K + k0, BsL + j * 2048);
    __syncthreads();
#pragma unroll
    for (int kk = 0; kk < 64; kk += 32) {
      bf16x8 af[4], bfr[NF];
#pragma unroll
      for (int t = 0; t < 4; ++t) {
        int R = frow_a + t * 16;   // R&7 == lane&7
        af[t] = *(const bf16x8*)((const char*)&As[0][0] + R * 128 + ((((kk + fk) * 2)) ^ rx));
      }
#pragma unroll
      for (int t = 0; t < NF; ++t) {
        int R = frow_b + t * 16;
        bfr[t] = *(const bf16x8*)((const char*)&Bs[0][0] + R * 128 + ((((kk + fk) * 2)) ^ rx));
      }
#pragma unroll
      for (int im = 0; im < 4; ++im)
#pragma unroll
        for (int jn = 0; jn < NF; ++jn)
          acc[im][jn] = __builtin_amdgcn_mfma_f32_16x16x32_bf16(af[im], bfr[jn], acc[im][jn], 0, 0, 0);
    }
    __syncthreads();
  }

  const int crow = (lane >> 4) * 4, ccol = lane & 15;
#pragma unroll
  for (int im = 0; im < 4; ++im)
#pragma unroll
    for (int jn = 0; jn < NF; ++jn) {
      OutT* Cp = C + (size_t)(row0 + wave_m * 64 + im * 16 + crow) * ldc
                   + col0 + wave_n * (TN / 2) + jn * 16 + ccol;
#pragma unroll
      for (int r = 0; r < 4; ++r) store_elem(acc[im][jn][r], Cp + (size_t)r * ldc);
    }
}

// ---------------------------------------------------------------------------
// Fused prep: z=0..3 -> weight transpose Wt[z][n][k] = W_z[k][n] (bf16);
// z=4..7 -> fp32->bf16 conversion of x, quarter slice each (1024 blocks total
// for the cvt = 4 blk/CU). ~7.6us, BW-bound (at floor).
// ---------------------------------------------------------------------------
__global__ __launch_bounds__(256) void prep(const float* __restrict__ x,
                                            const float* __restrict__ W0,
                                            const float* __restrict__ W1,
                                            const float* __restrict__ W2,
                                            const float* __restrict__ W3,
                                            __hip_bfloat16* __restrict__ xb,
                                            __hip_bfloat16* __restrict__ Wt) {
  __shared__ float tile[64][65];
  if (blockIdx.z >= 4) {
    const int base = (blockIdx.z - 4) * (MR * DM / 4);
    int i = ((blockIdx.y * gridDim.x + blockIdx.x) * 256 + threadIdx.x) * 4;
    const int stride = 16 * 16 * 256 * 4;
    for (; i < MR * DM / 4; i += stride) {
      float4 v = *(const float4*)(x + base + i);
      union { __hip_bfloat16 h[4]; uint2 u; } pk;
      pk.h[0] = __float2bfloat16(v.x); pk.h[1] = __float2bfloat16(v.y);
      pk.h[2] = __float2bfloat16(v.z); pk.h[3] = __float2bfloat16(v.w);
      *(uint2*)(xb + base + i) = pk.u;
    }
    return;
  }
  const float* W = blockIdx.z == 0 ? W0 : blockIdx.z == 1 ? W1 : blockIdx.z == 2 ? W2 : W3;
  __hip_bfloat16* out = Wt + (size_t)blockIdx.z * DM * DM;
  const int tid = threadIdx.x;
  const int kt = blockIdx.y * 64, nt = blockIdx.x * 64;
  const int lr = tid >> 6, lc = tid & 63;
#pragma unroll
  for (int i = 0; i < 16; ++i) {
    int k = i * 4 + lr;
    tile[k][lc] = W[(size_t)(kt + k) * DM + nt + lc];
  }
  __syncthreads();
  const int nl = tid >> 4, k4 = (tid & 15) * 4;
#pragma unroll
  for (int i = 0; i < 4; ++i) {
    int n = i * 16 + nl;
    union { __hip_bfloat16 h[4]; uint2 u; } pk;
#pragma unroll
    for (int xx = 0; xx < 4; ++xx) pk.h[xx] = __float2bfloat16(tile[k4 + xx][n]);
    *(uint2*)(out + (size_t)(nt + n) * DM + kt + k4) = pk.u;
  }
}

// ---------------------------------------------------------------------------
// Phase A (MFMA): Mc^T[j][i] = sum_{s in chunk} V[s][j] * K[s][i], bf16 out.
// A-frag = Vt[j][s], B-frag = Kt[i][s] (both transposed in LDS).
// One block per (c,h,b); 4 waves, each a 16-row strip of the 64x64 output.
// ---------------------------------------------------------------------------
__global__ __launch_bounds__(256) void chunk_kv(const __hip_bfloat16* __restrict__ QKV,
                                                __hip_bfloat16* __restrict__ Mc) {
  const int c = blockIdx.x, h = blockIdx.y, b = blockIdx.z;
  __shared__ short Kt[DH][LP];   // [i][s]
  __shared__ short Vt[DH][LP];   // [j][s]
  const int tid = threadIdx.x;
  const int lane = tid & 63, w = tid >> 6;
  const int r = tid >> 2, q16 = (tid & 3) * 16;
  const short* qkv = (const short*)QKV;
  const size_t grow = ((size_t)(b * TSEQ + c * CH + r)) * QKVLD + h * DH;
  short kk[16], vv[16];
  *(bf16x8*)&kk[0] = *(const bf16x8*)(qkv + grow + DM + q16);
  *(bf16x8*)&kk[8] = *(const bf16x8*)(qkv + grow + DM + q16 + 8);
  *(bf16x8*)&vv[0] = *(const bf16x8*)(qkv + grow + 2 * DM + q16);
  *(bf16x8*)&vv[8] = *(const bf16x8*)(qkv + grow + 2 * DM + q16 + 8);
#pragma unroll
  for (int j = 0; j < 16; ++j) {
    Kt[q16 + j][r] = kk[j];
    Vt[q16 + j][r] = vv[j];
  }
  __syncthreads();

  const int m = lane & 15, q = lane >> 4;
  bf16x8 af[2];
  af[0] = *(const bf16x8*)&Vt[16 * w + m][q * 8];
  af[1] = *(const bf16x8*)&Vt[16 * w + m][q * 8 + 32];
  f32x4 acc[4];
#pragma unroll
  for (int ct = 0; ct < 4; ++ct) acc[ct] = (f32x4){0.f, 0.f, 0.f, 0.f};
#pragma unroll
  for (int ct = 0; ct < 4; ++ct) {
    bf16x8 b0 = *(const bf16x8*)&Kt[ct * 16 + m][q * 8];
    bf16x8 b1 = *(const bf16x8*)&Kt[ct * 16 + m][q * 8 + 32];
    acc[ct] = __builtin_amdgcn_mfma_f32_16x16x32_bf16(af[0], b0, acc[ct], 0, 0, 0);
    acc[ct] = __builtin_amdgcn_mfma_f32_16x16x32_bf16(af[1], b1, acc[ct], 0, 0, 0);
  }
  __hip_bfloat16* out = Mc + ((size_t)((b * NHEAD + h) * NC + c)) * (DH * DH);
#pragma unroll
  for (int ct = 0; ct < 4; ++ct)
#pragma unroll
    for (int rr = 0; rr < 4; ++rr) {
      int row = 16 * w + q * 4 + rr, col = ct * 16 + m;
      out[(size_t)row * DH + col] = __float2bfloat16(acc[ct][rr]);
    }
}

// ---------------------------------------------------------------------------
// Phase B: exclusive prefix sum over 32 chunks (bf16 in, fp32 accum, bf16 out).
// grid (16, 32): each thread owns one of the 4096 state elements.
// Compile-time-unrolled: all 32 loads issue ahead of the serial add chain.
// (R7 lesson: fusing this into intra_attn as a runtime-bound loop exposes
//  per-iteration L2 latency on high-c blocks -> +5.8us. Keep standalone.)
// ---------------------------------------------------------------------------
__global__ __launch_bounds__(256) void scan_states(const __hip_bfloat16* __restrict__ Mc,
                                                   __hip_bfloat16* __restrict__ Spre) {
  const int bh = blockIdx.y;
  const size_t off = (size_t)bh * NC * (DH * DH) + blockIdx.x * 256 + threadIdx.x;
  const __hip_bfloat16* src = Mc + off;
  __hip_bfloat16* dst = Spre + off;
  float run = 0.f;
#pragma unroll
  for (int c = 0; c < NC; ++c) {
    dst[(size_t)c * (DH * DH)] = __float2bfloat16(run);
    run += __bfloat162float(src[(size_t)c * (DH * DH)]);
  }
}

// ---------------------------------------------------------------------------
// Phase C (MFMA): out = Q @ S + mask(Q @ K^T) @ V  per (b,h,chunk).
// Qs: [t][i] natural (reused for masked P [t][s]); Ks: [s][i] natural;
// Vt: [j][s]; St: [j][i] (= S^T as stored by scan). bf16 out.
// LDS 4*64*72*2 = 36 KB -> 4 blocks/CU.
// ---------------------------------------------------------------------------
__global__ __launch_bounds__(256) void intra_attn(const __hip_bfloat16* __restrict__ QKV,
                                                  const __hip_bfloat16* __restrict__ Spre,
                                                  __hip_bfloat16* __restrict__ O_) {
  const int c = blockIdx.x, h = blockIdx.y, b = blockIdx.z;
  __shared__ short Qs[CH][LP];
  __shared__ short Ks[CH][LP];
  __shared__ short Vt[DH][LP];
  __shared__ short St[DH][LP];
  const int tid = threadIdx.x;
  const int lane = tid & 63, w = tid >> 6;
  const int r = tid >> 2, q16 = (tid & 3) * 16;
  const short* qkv = (const short*)QKV;
  const size_t grow = ((size_t)(b * TSEQ + c * CH + r)) * QKVLD + h * DH;
  *(bf16x8*)&Qs[r][q16]     = *(const bf16x8*)(qkv + grow + q16);
  *(bf16x8*)&Qs[r][q16 + 8] = *(const bf16x8*)(qkv + grow + q16 + 8);
  *(bf16x8*)&Ks[r][q16]     = *(const bf16x8*)(qkv + grow + DM + q16);
  *(bf16x8*)&Ks[r][q16 + 8] = *(const bf16x8*)(qkv + grow + DM + q16 + 8);
  const short* Sg = (const short*)Spre + ((size_t)((b * NHEAD + h) * NC + c)) * (DH * DH);
  *(bf16x8*)&St[r][q16]     = *(const bf16x8*)(Sg + r * DH + q16);
  *(bf16x8*)&St[r][q16 + 8] = *(const bf16x8*)(Sg + r * DH + q16 + 8);
  short vv[16];
  *(bf16x8*)&vv[0] = *(const bf16x8*)(qkv + grow + 2 * DM + q16);
  *(bf16x8*)&vv[8] = *(const bf16x8*)(qkv + grow + 2 * DM + q16 + 8);
#pragma unroll
  for (int j = 0; j < 16; ++j) Vt[q16 + j][r] = vv[j];
  __syncthreads();

  const int m = lane & 15, q = lane >> 4;
  bf16x8 af[2];
  af[0] = *(const bf16x8*)&Qs[16 * w + m][q * 8];
  af[1] = *(const bf16x8*)&Qs[16 * w + m][q * 8 + 32];
  f32x4 acc[4], pacc[4];
#pragma unroll
  for (int ct = 0; ct < 4; ++ct) {
    acc[ct] = (f32x4){0.f, 0.f, 0.f, 0.f};
    pacc[ct] = (f32x4){0.f, 0.f, 0.f, 0.f};
  }
  // GEMM1: acc = Q @ S   (B-frag from St[j][i])
  // GEMM2: pacc = Q @ K^T (B-frag from Ks[s][i]) — shares af
#pragma unroll
  for (int ct = 0; ct < 4; ++ct) {
    bf16x8 s0 = *(const bf16x8*)&St[ct * 16 + m][q * 8];
    bf16x8 s1 = *(const bf16x8*)&St[ct * 16 + m][q * 8 + 32];
    acc[ct] = __builtin_amdgcn_mfma_f32_16x16x32_bf16(af[0], s0, acc[ct], 0, 0, 0);
    acc[ct] = __builtin_amdgcn_mfma_f32_16x16x32_bf16(af[1], s1, acc[ct], 0, 0, 0);
    bf16x8 k0 = *(const bf16x8*)&Ks[ct * 16 + m][q * 8];
    bf16x8 k1 = *(const bf16x8*)&Ks[ct * 16 + m][q * 8 + 32];
    pacc[ct] = __builtin_amdgcn_mfma_f32_16x16x32_bf16(af[0], k0, pacc[ct], 0, 0, 0);
    pacc[ct] = __builtin_amdgcn_mfma_f32_16x16x32_bf16(af[1], k1, pacc[ct], 0, 0, 0);
  }
  __syncthreads();   // all waves done reading Qs (af already in regs)
  // strict causal mask (keep s < t), write P as bf16 into Qs storage [t][s]
#pragma unroll
  for (int ct = 0; ct < 4; ++ct) {
    int col = ct * 16 + m;
#pragma unroll
    for (int rr = 0; rr < 4; ++rr) {
      int row = 16 * w + q * 4 + rr;
      float pv = (col < row) ? pacc[ct][rr] : 0.f;
      Qs[row][col] = f2bf(pv);
    }
  }
  __syncthreads();
  // GEMM3: acc += P @ V   (A-frag from Qs(P)[t][s], B-frag from Vt[j][s])
  bf16x8 pf[2];
  pf[0] = *(const bf16x8*)&Qs[16 * w + m][q * 8];
  pf[1] = *(const bf16x8*)&Qs[16 * w + m][q * 8 + 32];
#pragma unroll
  for (int ct = 0; ct < 4; ++ct) {
    bf16x8 v0 = *(const bf16x8*)&Vt[ct * 16 + m][q * 8];
    bf16x8 v1 = *(const bf16x8*)&Vt[ct * 16 + m][q * 8 + 32];
    acc[ct] = __builtin_amdgcn_mfma_f32_16x16x32_bf16(pf[0], v0, acc[ct], 0, 0, 0);
    acc[ct] = __builtin_amdgcn_mfma_f32_16x16x32_bf16(pf[1], v1, acc[ct], 0, 0, 0);
  }
  __hip_bfloat16* Ob = O_ + ((size_t)(b * TSEQ + c * CH)) * DM + h * DH;
#pragma unroll
  for (int ct = 0; ct < 4; ++ct)
#pragma unroll
    for (int rr = 0; rr < 4; ++rr) {
      int row = 16 * w + q * 4 + rr, col = ct * 16 + m;
      Ob[(size_t)row * DM + col] = __float2bfloat16(acc[ct][rr]);
    }
}

// ---------------------------------------------------------------------------
extern "C" void kernel_launch(void* const* d_in, const int* in_sizes, int n_in,
                              void* d_out, int out_size, void* d_ws, size_t ws_size,
                              hipStream_t stream) {
  const float* x  = (const float*)d_in[0];
  const float* Wq = (const float*)d_in[1];
  const float* Wk = (const float*)d_in[2];
  const float* Wv = (const float*)d_in[3];
  const float* Wo = (const float*)d_in[4];
  float* out = (float*)d_out;

  char* ws = (char*)d_ws;
  __hip_bfloat16* xb    = (__hip_bfloat16*)ws;  ws += (size_t)MR * DM * 2;              // 8 MB
  __hip_bfloat16* WtAll = (__hip_bfloat16*)ws;  ws += (size_t)4 * DM * DM * 2;          // 8 MB
  __hip_bfloat16* qkvb  = (__hip_bfloat16*)ws;  ws += (size_t)MR * QKVLD * 2;           // 24 MB
  __hip_bfloat16* Mc    = (__hip_bfloat16*)ws;  ws += (size_t)BATCH * NHEAD * NC * DH * DH * 2; // 8 MB
  __hip_bfloat16* Spre  = (__hip_bfloat16*)ws;  ws += (size_t)BATCH * NHEAD * NC * DH * DH * 2; // 8 MB
  __hip_bfloat16* aob   = (__hip_bfloat16*)ws;  ws += (size_t)MR * DM * 2;              // 8 MB

  // fused x-cvt (4 slices) + 4 weight transposes (one launch)
  prep<<<dim3(16, 16, 8), 256, 0, stream>>>(x, Wq, Wk, Wv, Wo, xb, WtAll);

  // fused QKV projection: [4096,1024] @ [1024,3072] -> bf16 [4096,3072]
  gemm_bf16<__hip_bfloat16, 128><<<dim3(QKVLD / 128, MR / 128), 256, 0, stream>>>(
      (const short*)xb, (const short*)WtAll, qkvb, MR, QKVLD, DM, QKVLD);

  chunk_kv<<<dim3(NC, NHEAD, BATCH), 256, 0, stream>>>(qkvb, Mc);
  scan_states<<<dim3(DH * DH / 256, BATCH * NHEAD), 256, 0, stream>>>(Mc, Spre);
  intra_attn<<<dim3(NC, NHEAD, BATCH), 256, 0, stream>>>(qkvb, Spre, aob);

  // output projection: [4096,1024] @ [1024,1024] -> fp32 [4096,1024]
  // TN=64 tile: grid (16,32)=512 blocks = 2 blk/CU.
  gemm_bf16<float, 64><<<dim3(DM / 64, MR / 128), 256, 0, stream>>>(
      (const short*)aob, (const short*)(WtAll + (size_t)3 * DM * DM), out, MR, DM, DM, DM);
}

// Round 16
// 151.397 us; speedup vs baseline: 1.0045x; 1.0045x over previous
//
#include <hip/hip_runtime.h>
#include <hip/hip_bf16.h>

// Problem constants (QuadraticAttention): B=2, T=2048, D_MODEL=1024, H=16, d=64
#define TSEQ   2048
#define DM     1024
#define NHEAD  16
#define DH     64
#define BATCH  2
#define MR     (BATCH * TSEQ)   // 4096 rows
#define CH     64               // attention chunk length
#define NC     (TSEQ / CH)      // 32 chunks per sequence
#define QKVLD  (3 * DM)         // 3072: q|k|v packed per token row
#define LP     72               // padded LDS row stride (bf16), 144 B, 16B-aligned

typedef __attribute__((ext_vector_type(8))) short bf16x8;
typedef __attribute__((ext_vector_type(4))) float f32x4;

__device__ __forceinline__ short f2bf(float x) {
  __hip_bfloat16 h = __float2bfloat16(x);
  return *reinterpret_cast<short*>(&h);
}

// ---------------------------------------------------------------------------
// async global->LDS, 16 bytes per lane (wave-uniform base + lane*16).
// ---------------------------------------------------------------------------
__device__ __forceinline__ void stage16(const void* g, void* l) {
  __builtin_amdgcn_global_load_lds(
      (const __attribute__((address_space(1))) void*)g,
      (__attribute__((address_space(3))) void*)l, 16, 0, 0);
}

__device__ __forceinline__ void store_elem(float v, float* p) { *p = v; }
__device__ __forceinline__ void store_elem(float v, __hip_bfloat16* p) { *p = __float2bfloat16(v); }

// ---------------------------------------------------------------------------
// bf16 MFMA GEMM (measured-best body; 153.5/153.1/152.7/152.4/154.8/152.0/
// 152.1us over 7 runs of identical code -> mean 153.0, noise +-1.5us):
// C[M,N] = A[M,K] @ B[K,N].  A: bf16 [M,K]. Bt: bf16 [N,K]. OutT = f32/bf16.
// Tile 128 x TN, BK=64 (16 K-iters at K=1024), 256 threads = 4 waves (2x2).
// SESSION LEDGER (do not re-derive):
//  - R6: BK=32 3-buffer counted-vmcnt pipeline = +3.4us REGRESSION (2x barrier
//    count, 4-way LDS conflicts from (row&3) XOR, sched_barrier pinning).
//  - R7: scan-fused-into-intra = +5.8us REGRESSION (runtime-bound serial
//    prefix loop exposes per-iter L2 latency; unrollable standalone scan wins).
//  - R8-R15: this body confirmed best 7x. Catalog cross-check: all
//    128^2-family alternatives (2ph, dbuf m99/m100, BK=128 m132) measure
//    at-or-below. Only proven step past it is the 8-phase 256^2 template;
//    staging choreography not derivable race-free from prose (m152).
//  - C-store packing impossible (lane holds 4 ROWS of one col, stride ldc);
//    chunk_kv+scan fusion needs grid sync (R7 failure mode); 256-wide tiles
//    kill the m114 wave-overlap. Dependency chain is fully serial.
//  - Any |delta| < ~2us is unadjudicable (noise band spans 2.8us).
// LDS rows are 128 B; T2 XOR swizzle (byte ^= (row&7)<<4) applied BOTH sides
// per rule #21: linear LDS dest for global_load_lds + inverse-XOR'd SOURCE
// column at staging + XOR'd byte address at ds_read (involution).
// XCD-aware bijective blockIdx swizzle (m204) for per-XCD L2 locality.
// ---------------------------------------------------------------------------
template <typename OutT, int TN>
__global__ __launch_bounds__(256) void gemm_bf16(const short* __restrict__ A,
                                                 const short* __restrict__ Bt,
                                                 OutT* __restrict__ C,
                                                 int M, int N, int K, int ldc) {
  constexpr int NF = TN / 32;        // B frags per wave (4 or 2)
  constexpr int BSW = TN / 32;       // B staging sweeps (TN*64*2B / 4096B)
  __shared__ short As[128][64];      // 16 KB, XOR-swizzled within 128B rows
  __shared__ short Bs[TN][64];       // 16 or 8 KB, same swizzle
  const int tid = threadIdx.x;
  const int lane = tid & 63, wid = tid >> 6;
  const int wave_m = wid >> 1, wave_n = wid & 1;

  // XCD-aware bijective swizzle: contiguous tile chunk per XCD (8 XCDs).
  const unsigned nwg = gridDim.x * gridDim.y;
  const unsigned lin = blockIdx.y * gridDim.x + blockIdx.x;
  const unsigned q8 = nwg >> 3, r8 = nwg & 7;
  const unsigned xcd = lin & 7, idx = lin >> 3;
  const unsigned swz = (xcd < r8 ? xcd * (q8 + 1) : r8 * (q8 + 1) + (xcd - r8) * q8) + idx;
  const int bx = swz % gridDim.x, by = swz / gridDim.x;

  const int row0 = by * 128, col0 = bx * TN;

  // Staging: thread t writes LDS 16B chunk (t&7) of row (t>>3), +32 rows per
  // sweep. Source column is XOR-swizzled: chunk_src = (t&7) ^ (row&7); since
  // sweep stride 32 kills &7, it is constant per thread.
  const int sr = tid >> 3;                          // 0..31
  const int scs = ((tid & 7) ^ (sr & 7)) * 8;       // source col (shorts)
  const short* Ag0 = A + (size_t)(row0 + sr) * K + scs;
  const short* Bg0 = Bt + (size_t)(col0 + sr) * K + scs;
  short* AsL = &As[0][0] + tid * 8;
  short* BsL = &Bs[0][0] + tid * 8;

  f32x4 acc[4][NF];
#pragma unroll
  for (int i = 0; i < 4; ++i)
#pragma unroll
    for (int j = 0; j < NF; ++j) acc[i][j] = (f32x4){0.f, 0.f, 0.f, 0.f};

  const int frow_a = wave_m * 64 + (lane & 15);
  const int frow_b = wave_n * (TN / 2) + (lane & 15);
  const int fk = (lane >> 4) * 8;                   // shorts within K-substep
  const int rx = (lane & 7) << 4;                   // read-side XOR (row&7)<<4

  for (int k0 = 0; k0 < K; k0 += 64) {
#pragma unroll
    for (int j = 0; j < 4; ++j)
      stage16(Ag0 + (size_t)(j * 32) * K + k0, AsL + j * 2048);
#pragma unroll
    for (int j = 0; j < BSW; ++j)
      stage16(Bg0 + (size_t)(j * 32) * K + k0, BsL + j * 2048);
    __syncthreads();
#pragma unroll
    for (int kk = 0; kk < 64; kk += 32) {
      bf16x8 af[4], bfr[NF];
#pragma unroll
      for (int t = 0; t < 4; ++t) {
        int R = frow_a + t * 16;   // R&7 == lane&7
        af[t] = *(const bf16x8*)((const char*)&As[0][0] + R * 128 + ((((kk + fk) * 2)) ^ rx));
      }
#pragma unroll
      for (int t = 0; t < NF; ++t) {
        int R = frow_b + t * 16;
        bfr[t] = *(const bf16x8*)((const char*)&Bs[0][0] + R * 128 + ((((kk + fk) * 2)) ^ rx));
      }
#pragma unroll
      for (int im = 0; im < 4; ++im)
#pragma unroll
        for (int jn = 0; jn < NF; ++jn)
          acc[im][jn] = __builtin_amdgcn_mfma_f32_16x16x32_bf16(af[im], bfr[jn], acc[im][jn], 0, 0, 0);
    }
    __syncthreads();
  }

  const int crow = (lane >> 4) * 4, ccol = lane & 15;
#pragma unroll
  for (int im = 0; im < 4; ++im)
#pragma unroll
    for (int jn = 0; jn < NF; ++jn) {
      OutT* Cp = C + (size_t)(row0 + wave_m * 64 + im * 16 + crow) * ldc
                   + col0 + wave_n * (TN / 2) + jn * 16 + ccol;
#pragma unroll
      for (int r = 0; r < 4; ++r) store_elem(acc[im][jn][r], Cp + (size_t)r * ldc);
    }
}

// ---------------------------------------------------------------------------
// Fused prep: z=0..3 -> weight transpose Wt[z][n][k] = W_z[k][n] (bf16);
// z=4..7 -> fp32->bf16 conversion of x, quarter slice each (1024 blocks total
// for the cvt = 4 blk/CU). ~7.6us, BW-bound (at floor).
// ---------------------------------------------------------------------------
__global__ __launch_bounds__(256) void prep(const float* __restrict__ x,
                                            const float* __restrict__ W0,
                                            const float* __restrict__ W1,
                                            const float* __restrict__ W2,
                                            const float* __restrict__ W3,
                                            __hip_bfloat16* __restrict__ xb,
                                            __hip_bfloat16* __restrict__ Wt) {
  __shared__ float tile[64][65];
  if (blockIdx.z >= 4) {
    const int base = (blockIdx.z - 4) * (MR * DM / 4);
    int i = ((blockIdx.y * gridDim.x + blockIdx.x) * 256 + threadIdx.x) * 4;
    const int stride = 16 * 16 * 256 * 4;
    for (; i < MR * DM / 4; i += stride) {
      float4 v = *(const float4*)(x + base + i);
      union { __hip_bfloat16 h[4]; uint2 u; } pk;
      pk.h[0] = __float2bfloat16(v.x); pk.h[1] = __float2bfloat16(v.y);
      pk.h[2] = __float2bfloat16(v.z); pk.h[3] = __float2bfloat16(v.w);
      *(uint2*)(xb + base + i) = pk.u;
    }
    return;
  }
  const float* W = blockIdx.z == 0 ? W0 : blockIdx.z == 1 ? W1 : blockIdx.z == 2 ? W2 : W3;
  __hip_bfloat16* out = Wt + (size_t)blockIdx.z * DM * DM;
  const int tid = threadIdx.x;
  const int kt = blockIdx.y * 64, nt = blockIdx.x * 64;
  const int lr = tid >> 6, lc = tid & 63;
#pragma unroll
  for (int i = 0; i < 16; ++i) {
    int k = i * 4 + lr;
    tile[k][lc] = W[(size_t)(kt + k) * DM + nt + lc];
  }
  __syncthreads();
  const int nl = tid >> 4, k4 = (tid & 15) * 4;
#pragma unroll
  for (int i = 0; i < 4; ++i) {
    int n = i * 16 + nl;
    union { __hip_bfloat16 h[4]; uint2 u; } pk;
#pragma unroll
    for (int xx = 0; xx < 4; ++xx) pk.h[xx] = __float2bfloat16(tile[k4 + xx][n]);
    *(uint2*)(out + (size_t)(nt + n) * DM + kt + k4) = pk.u;
  }
}

// ---------------------------------------------------------------------------
// Phase A (MFMA): Mc^T[j][i] = sum_{s in chunk} V[s][j] * K[s][i], bf16 out.
// A-frag = Vt[j][s], B-frag = Kt[i][s] (both transposed in LDS).
// One block per (c,h,b); 4 waves, each a 16-row strip of the 64x64 output.
// ---------------------------------------------------------------------------
__global__ __launch_bounds__(256) void chunk_kv(const __hip_bfloat16* __restrict__ QKV,
                                                __hip_bfloat16* __restrict__ Mc) {
  const int c = blockIdx.x, h = blockIdx.y, b = blockIdx.z;
  __shared__ short Kt[DH][LP];   // [i][s]
  __shared__ short Vt[DH][LP];   // [j][s]
  const int tid = threadIdx.x;
  const int lane = tid & 63, w = tid >> 6;
  const int r = tid >> 2, q16 = (tid & 3) * 16;
  const short* qkv = (const short*)QKV;
  const size_t grow = ((size_t)(b * TSEQ + c * CH + r)) * QKVLD + h * DH;
  short kk[16], vv[16];
  *(bf16x8*)&kk[0] = *(const bf16x8*)(qkv + grow + DM + q16);
  *(bf16x8*)&kk[8] = *(const bf16x8*)(qkv + grow + DM + q16 + 8);
  *(bf16x8*)&vv[0] = *(const bf16x8*)(qkv + grow + 2 * DM + q16);
  *(bf16x8*)&vv[8] = *(const bf16x8*)(qkv + grow + 2 * DM + q16 + 8);
#pragma unroll
  for (int j = 0; j < 16; ++j) {
    Kt[q16 + j][r] = kk[j];
    Vt[q16 + j][r] = vv[j];
  }
  __syncthreads();

  const int m = lane & 15, q = lane >> 4;
  bf16x8 af[2];
  af[0] = *(const bf16x8*)&Vt[16 * w + m][q * 8];
  af[1] = *(const bf16x8*)&Vt[16 * w + m][q * 8 + 32];
  f32x4 acc[4];
#pragma unroll
  for (int ct = 0; ct < 4; ++ct) acc[ct] = (f32x4){0.f, 0.f, 0.f, 0.f};
#pragma unroll
  for (int ct = 0; ct < 4; ++ct) {
    bf16x8 b0 = *(const bf16x8*)&Kt[ct * 16 + m][q * 8];
    bf16x8 b1 = *(const bf16x8*)&Kt[ct * 16 + m][q * 8 + 32];
    acc[ct] = __builtin_amdgcn_mfma_f32_16x16x32_bf16(af[0], b0, acc[ct], 0, 0, 0);
    acc[ct] = __builtin_amdgcn_mfma_f32_16x16x32_bf16(af[1], b1, acc[ct], 0, 0, 0);
  }
  __hip_bfloat16* out = Mc + ((size_t)((b * NHEAD + h) * NC + c)) * (DH * DH);
#pragma unroll
  for (int ct = 0; ct < 4; ++ct)
#pragma unroll
    for (int rr = 0; rr < 4; ++rr) {
      int row = 16 * w + q * 4 + rr, col = ct * 16 + m;
      out[(size_t)row * DH + col] = __float2bfloat16(acc[ct][rr]);
    }
}

// ---------------------------------------------------------------------------
// Phase B: exclusive prefix sum over 32 chunks (bf16 in, fp32 accum, bf16 out).
// grid (16, 32): each thread owns one of the 4096 state elements.
// Compile-time-unrolled: all 32 loads issue ahead of the serial add chain.
// (R7 lesson: fusing this into intra_attn as a runtime-bound loop exposes
//  per-iteration L2 latency on high-c blocks -> +5.8us. Keep standalone.)
// ---------------------------------------------------------------------------
__global__ __launch_bounds__(256) void scan_states(const __hip_bfloat16* __restrict__ Mc,
                                                   __hip_bfloat16* __restrict__ Spre) {
  const int bh = blockIdx.y;
  const size_t off = (size_t)bh * NC * (DH * DH) + blockIdx.x * 256 + threadIdx.x;
  const __hip_bfloat16* src = Mc + off;
  __hip_bfloat16* dst = Spre + off;
  float run = 0.f;
#pragma unroll
  for (int c = 0; c < NC; ++c) {
    dst[(size_t)c * (DH * DH)] = __float2bfloat16(run);
    run += __bfloat162float(src[(size_t)c * (DH * DH)]);
  }
}

// ---------------------------------------------------------------------------
// Phase C (MFMA): out = Q @ S + mask(Q @ K^T) @ V  per (b,h,chunk).
// Qs: [t][i] natural (reused for masked P [t][s]); Ks: [s][i] natural;
// Vt: [j][s]; St: [j][i] (= S^T as stored by scan). bf16 out.
// LDS 4*64*72*2 = 36 KB -> 4 blocks/CU.
// ---------------------------------------------------------------------------
__global__ __launch_bounds__(256) void intra_attn(const __hip_bfloat16* __restrict__ QKV,
                                                  const __hip_bfloat16* __restrict__ Spre,
                                                  __hip_bfloat16* __restrict__ O_) {
  const int c = blockIdx.x, h = blockIdx.y, b = blockIdx.z;
  __shared__ short Qs[CH][LP];
  __shared__ short Ks[CH][LP];
  __shared__ short Vt[DH][LP];
  __shared__ short St[DH][LP];
  const int tid = threadIdx.x;
  const int lane = tid & 63, w = tid >> 6;
  const int r = tid >> 2, q16 = (tid & 3) * 16;
  const short* qkv = (const short*)QKV;
  const size_t grow = ((size_t)(b * TSEQ + c * CH + r)) * QKVLD + h * DH;
  *(bf16x8*)&Qs[r][q16]     = *(const bf16x8*)(qkv + grow + q16);
  *(bf16x8*)&Qs[r][q16 + 8] = *(const bf16x8*)(qkv + grow + q16 + 8);
  *(bf16x8*)&Ks[r][q16]     = *(const bf16x8*)(qkv + grow + DM + q16);
  *(bf16x8*)&Ks[r][q16 + 8] = *(const bf16x8*)(qkv + grow + DM + q16 + 8);
  const short* Sg = (const short*)Spre + ((size_t)((b * NHEAD + h) * NC + c)) * (DH * DH);
  *(bf16x8*)&St[r][q16]     = *(const bf16x8*)(Sg + r * DH + q16);
  *(bf16x8*)&St[r][q16 + 8] = *(const bf16x8*)(Sg + r * DH + q16 + 8);
  short vv[16];
  *(bf16x8*)&vv[0] = *(const bf16x8*)(qkv + grow + 2 * DM + q16);
  *(bf16x8*)&vv[8] = *(const bf16x8*)(qkv + grow + 2 * DM + q16 + 8);
#pragma unroll
  for (int j = 0; j < 16; ++j) Vt[q16 + j][r] = vv[j];
  __syncthreads();

  const int m = lane & 15, q = lane >> 4;
  bf16x8 af[2];
  af[0] = *(const bf16x8*)&Qs[16 * w + m][q * 8];
  af[1] = *(const bf16x8*)&Qs[16 * w + m][q * 8 + 32];
  f32x4 acc[4], pacc[4];
#pragma unroll
  for (int ct = 0; ct < 4; ++ct) {
    acc[ct] = (f32x4){0.f, 0.f, 0.f, 0.f};
    pacc[ct] = (f32x4){0.f, 0.f, 0.f, 0.f};
  }
  // GEMM1: acc = Q @ S   (B-frag from St[j][i])
  // GEMM2: pacc = Q @ K^T (B-frag from Ks[s][i]) — shares af
#pragma unroll
  for (int ct = 0; ct < 4; ++ct) {
    bf16x8 s0 = *(const bf16x8*)&St[ct * 16 + m][q * 8];
    bf16x8 s1 = *(const bf16x8*)&St[ct * 16 + m][q * 8 + 32];
    acc[ct] = __builtin_amdgcn_mfma_f32_16x16x32_bf16(af[0], s0, acc[ct], 0, 0, 0);
    acc[ct] = __builtin_amdgcn_mfma_f32_16x16x32_bf16(af[1], s1, acc[ct], 0, 0, 0);
    bf16x8 k0 = *(const bf16x8*)&Ks[ct * 16 + m][q * 8];
    bf16x8 k1 = *(const bf16x8*)&Ks[ct * 16 + m][q * 8 + 32];
    pacc[ct] = __builtin_amdgcn_mfma_f32_16x16x32_bf16(af[0], k0, pacc[ct], 0, 0, 0);
    pacc[ct] = __builtin_amdgcn_mfma_f32_16x16x32_bf16(af[1], k1, pacc[ct], 0, 0, 0);
  }
  __syncthreads();   // all waves done reading Qs (af already in regs)
  // strict causal mask (keep s < t), write P as bf16 into Qs storage [t][s]
#pragma unroll
  for (int ct = 0; ct < 4; ++ct) {
    int col = ct * 16 + m;
#pragma unroll
    for (int rr = 0; rr < 4; ++rr) {
      int row = 16 * w + q * 4 + rr;
      float pv = (col < row) ? pacc[ct][rr] : 0.f;
      Qs[row][col] = f2bf(pv);
    }
  }
  __syncthreads();
  // GEMM3: acc += P @ V   (A-frag from Qs(P)[t][s], B-frag from Vt[j][s])
  bf16x8 pf[2];
  pf[0] = *(const bf16x8*)&Qs[16 * w + m][q * 8];
  pf[1] = *(const bf16x8*)&Qs[16 * w + m][q * 8 + 32];
#pragma unroll
  for (int ct = 0; ct < 4; ++ct) {
    bf16x8 v0 = *(const bf16x8*)&Vt[ct * 16 + m][q * 8];
    bf16x8 v1 = *(const bf16x8*)&Vt[ct * 16 + m][q * 8 + 32];
    acc[ct] = __builtin_amdgcn_mfma_f32_16x16x32_bf16(pf[0], v0, acc[ct], 0, 0, 0);
    acc[ct] = __builtin_amdgcn_mfma_f32_16x16x32_bf16(pf[1], v1, acc[ct], 0, 0, 0);
  }
  __hip_bfloat16* Ob = O_ + ((size_t)(b * TSEQ + c * CH)) * DM + h * DH;
#pragma unroll
  for (int ct = 0; ct < 4; ++ct)
#pragma unroll
    for (int rr = 0; rr < 4; ++rr) {
      int row = 16 * w + q * 4 + rr, col = ct * 16 + m;
      Ob[(size_t)row * DM + col] = __float2bfloat16(acc[ct][rr]);
    }
}

// ---------------------------------------------------------------------------
extern "C" void kernel_launch(void* const* d_in, const int* in_sizes, int n_in,
                              void* d_out, int out_size, void* d_ws, size_t ws_size,
                              hipStream_t stream) {
  const float* x  = (const float*)d_in[0];
  const float* Wq = (const float*)d_in[1];
  const float* Wk = (const float*)d_in[2];
  const float* Wv = (const float*)d_in[3];
  const float* Wo = (const float*)d_in[4];
  float* out = (float*)d_out;

  char* ws = (char*)d_ws;
  __hip_bfloat16* xb    = (__hip_bfloat16*)ws;  ws += (size_t)MR * DM * 2;              // 8 MB
  __hip_bfloat16* WtAll = (__hip_bfloat16*)ws;  ws += (size_t)4 * DM * DM * 2;          // 8 MB
  __hip_bfloat16* qkvb  = (__hip_bfloat16*)ws;  ws += (size_t)MR * QKVLD * 2;           // 24 MB
  __hip_bfloat16* Mc    = (__hip_bfloat16*)ws;  ws += (size_t)BATCH * NHEAD * NC * DH * DH * 2; // 8 MB
  __hip_bfloat16* Spre  = (__hip_bfloat16*)ws;  ws += (size_t)BATCH * NHEAD * NC * DH * DH * 2; // 8 MB
  __hip_bfloat16* aob   = (__hip_bfloat16*)ws;  ws += (size_t)MR * DM * 2;              // 8 MB

  // fused x-cvt (4 slices) + 4 weight transposes (one launch)
  prep<<<dim3(16, 16, 8), 256, 0, stream>>>(x, Wq, Wk, Wv, Wo, xb, WtAll);

  // fused QKV projection: [4096,1024] @ [1024,3072] -> bf16 [4096,3072]
  gemm_bf16<__hip_bfloat16, 128><<<dim3(QKVLD / 128, MR / 128), 256, 0, stream>>>(
      (const short*)xb, (const short*)WtAll, qkvb, MR, QKVLD, DM, QKVLD);

  chunk_kv<<<dim3(NC, NHEAD, BATCH), 256, 0, stream>>>(qkvb, Mc);
  scan_states<<<dim3(DH * DH / 256, BATCH * NHEAD), 256, 0, stream>>>(Mc, Spre);
  intra_attn<<<dim3(NC, NHEAD, BATCH), 256, 0, stream>>>(qkvb, Spre, aob);

  // output projection: [4096,1024] @ [1024,1024] -> fp32 [4096,1024]
  // TN=64 tile: grid (16,32)=512 blocks = 2 blk/CU.
  gemm_bf16<float, 64><<<dim3(DM / 64, MR / 128), 256, 0, stream>>>(
      (const short*)aob, (const short*)(WtAll + (size_t)3 * DM * DM), out, MR, DM, DM, DM);
}